// Round 12
// baseline (205.824 us; speedup 1.0000x reference)
//
#include <hip/hip_runtime.h>
#include <math.h>
#include <stdint.h>

#define T_STEPS 256
#define BS      512
#define N       2048
#define BLOCK   256               // 4 waves; block owns TWO batch elements
#define FUDGE   1e-4f

// R19: dual-element blocks. R17/R18 showed the 4-wave single-element config
// is pinned at ~121us: ~60% VALU issue, ~40% exchange serial latency, and
// micro-scheduling can't reduce both. This round: grid=256 blocks, each
// handling elements {2blk, 2blk+1}. The two scans share: coefficient regs
// (same tid slice), hb=cb+qsc*cq, qlp/ylp/sp/rsp (element-independent),
// the barrier, and the LDS exchange (lane63 publishes {suA,shA,suB,shB} as
// ONE ds_write_b128; combine covers both). Per-element exchange cost halves;
// solo-wave latency (1 wave/SIMD) is hidden by the partner element's
// independent instruction stream (ILP replaces TLP). nz pair via one
// s_load_dwordx2; output pair via one global_store_dwordx2 (adjacent).
__global__ __launch_bounds__(BLOCK)
void legacy_elbo_scan_kernel(
    const float* __restrict__ noises,   // [T, BS]
    const float* __restrict__ ys,       // [T]
    const float* __restrict__ qs,       // [T]
    const float* __restrict__ z_biases, // [N]
    const float* __restrict__ w_in,     // [N]
    const float* __restrict__ w_inq,    // [N]
    const float* __restrict__ p_llr,
    const float* __restrict__ p_llrd,
    const float* __restrict__ p_sigb,
    const float* __restrict__ p_oscale,
    const float* __restrict__ p_ufs,
    const float* __restrict__ p_lwd,
    const float* __restrict__ p_qscale,
    const float* __restrict__ p_tauq,
    const float* __restrict__ p_tauy,
    float* __restrict__ out)            // [T, BS]
{
    const int tid = threadIdx.x;
    const int blk = blockIdx.x;         // element pair {2blk, 2blk+1}

    __shared__ float red_lds[32];       // [parity 2][wave 4][suA,shA,suB,shB]
    if (tid < 32) red_lds[tid] = 0.0f;  // keep allocation live at offset 0
    __syncthreads();

    const float sigb    = p_sigb[0];
    const float lr0     = expf(p_llr[0]);
    const float lr_decay= expf(p_llrd[0]);
    const float wd      = expf(p_lwd[0]);
    const float rwd     = 1.0f / wd;
    const float tauq    = 1.0f + log1pf(expf(p_tauq[0]));
    const float tauy    = 1.0f + log1pf(expf(p_tauy[0]));
    const float omtq    = 1.0f - tauq;
    const float omty    = 1.0f - tauy;
    const float qscale  = p_qscale[0];
    const float ufsm1   = p_ufs[0] - 1.0f;   // x' = pre + (ufs-1)*u
    const float oscale  = p_oscale[0];
    const float nld2    = -lr_decay * 1.4426950408889634f;  // exp->exp2 fold

    const float* nzp = noises + 2 * blk;     // noise column pair base
    const int    ovo = blk * 8;              // byte offset of out[0][2blk]

    asm volatile(
        // -------- init: ids, masks, ds addrs, coeff + scalar loads ----------
        "v_lshrrev_b32 v3, 6, %[vtid]\n\t"          // wid
        "v_lshlrev_b32 v4, 4, v3\n\t"               // ds write addr = wid*16
        "v_and_b32 v7, 63, %[vtid]\n\t"
        "v_cmp_eq_u32 vcc, 63, v7\n\t"              // lane-63 mask
        "s_mov_b64 s[74:75], vcc\n\t"
        "v_cmp_eq_u32 vcc, 0, %[vtid]\n\t"          // tid==0 mask
        "s_mov_b64 s[76:77], vcc\n\t"
        "v_mov_b32 v5, 0\n\t"                       // ds read base, parity 0
        "v_lshlrev_b32 v1, 4, %[vtid]\n\t"
        "v_add_u32 v2, 0x1000, v1\n\t"
        "global_load_dwordx4 v[56:59], v1, %[pzb]\n\t"   // cb (pre-scale)
        "global_load_dwordx4 v[60:63], v2, %[pzb]\n\t"
        "global_load_dwordx4 v[40:43], v1, %[pwi]\n\t"   // cw
        "global_load_dwordx4 v[44:47], v2, %[pwi]\n\t"
        "global_load_dwordx4 v[48:51], v1, %[pwq]\n\t"   // cq
        "global_load_dwordx4 v[52:55], v2, %[pwq]\n\t"
        // scalar triple buffer: A=t0 {s66,s67,s[68:69]}, B=t1 {s70,s71,s[54:55]},
        // C=t2 {s50,s51,s[52:53]}  (y, q, nz-pair)
        "s_load_dword s66, %[pys], 0x0\n\t"
        "s_load_dword s67, %[pqs], 0x0\n\t"
        "s_load_dwordx2 s[68:69], %[pnz], 0x0\n\t"
        "s_load_dword s70, %[pys], 0x4\n\t"
        "s_load_dword s71, %[pqs], 0x4\n\t"
        "s_load_dwordx2 s[54:55], %[pnz], 0x800\n\t"
        "s_load_dword s50, %[pys], 0x8\n\t"
        "s_load_dword s51, %[pqs], 0x8\n\t"
        "s_load_dwordx2 s[52:53], %[pnz], 0x1000\n\t"
        "s_mov_b32 s61, 12\n\t"                     // y/q byte off for t3
        "s_mov_b32 s62, 0x1800\n\t"                 // nz byte off for t3
        "s_mov_b32 s60, 0\n\t"
        "s_waitcnt vmcnt(0) lgkmcnt(0)\n\t"
        // cb *= sigma_b
        "v_mul_f32 v56, %[osg], v56\n\t" "v_mul_f32 v57, %[osg], v57\n\t"
        "v_mul_f32 v58, %[osg], v58\n\t" "v_mul_f32 v59, %[osg], v59\n\t"
        "v_mul_f32 v60, %[osg], v60\n\t" "v_mul_f32 v61, %[osg], v61\n\t"
        "v_mul_f32 v62, %[osg], v62\n\t" "v_mul_f32 v63, %[osg], v63\n\t"
        // zero wA v64-71, wB v96-103
        "v_mov_b32 v64, 0\n\t" "v_mov_b32 v65, 0\n\t" "v_mov_b32 v66, 0\n\t" "v_mov_b32 v67, 0\n\t"
        "v_mov_b32 v68, 0\n\t" "v_mov_b32 v69, 0\n\t" "v_mov_b32 v70, 0\n\t" "v_mov_b32 v71, 0\n\t"
        "v_mov_b32 v96, 0\n\t" "v_mov_b32 v97, 0\n\t" "v_mov_b32 v98, 0\n\t" "v_mov_b32 v99, 0\n\t"
        "v_mov_b32 v100, 0\n\t" "v_mov_b32 v101, 0\n\t" "v_mov_b32 v102, 0\n\t" "v_mov_b32 v103, 0\n\t"
        // state: qlp v104, ylp v105, uA v106, uB v107, lrmA v108, lrmB v109,
        //        sp v110, rsp v111, preA v112, preB v113, elpreA v114, elpreB v115
        "v_mov_b32 v105, 0\n\t"
        "v_mov_b32 v108, 1.0\n\t" "v_mov_b32 v109, 1.0\n\t"
        "v_mov_b32 v110, 1.0\n\t" "v_mov_b32 v111, 1.0\n\t"
        "v_mov_b32 v6, %[ovo]\n\t"
        // qlp0 = tauq*q0 ; qsc pair v[12:13]
        "v_mul_f32 v104, s67, %[otq]\n\t"
        "v_mul_f32 v12, v104, %[oq]\n\t"
        "v_mov_b32 v13, v12\n\t"
        // hb0 = cb + qsc*cq  (v80-87)
        "v_pk_fma_f32 v[80:81], v[12:13], v[48:49], v[56:57]\n\t"
        "v_pk_fma_f32 v[82:83], v[12:13], v[50:51], v[58:59]\n\t"
        "v_pk_fma_f32 v[84:85], v[12:13], v[52:53], v[60:61]\n\t"
        "v_pk_fma_f32 v[86:87], v[12:13], v[54:55], v[62:63]\n\t"
        // xA0 = nzA0 (v[8:9]), xB0 = nzB0 (v[10:11])
        "v_mov_b32 v8, s68\n\t"  "v_mov_b32 v9, v8\n\t"
        "v_mov_b32 v10, s69\n\t" "v_mov_b32 v11, v10\n\t"
        // ---------------- main scan loop (one iter = one t, TWO elements) ----
        "Lelbo5:\n\t"
        // hA (v72-79) and hB (v88-95), interleaved; hb shared
        "v_pk_fma_f32 v[72:73], v[8:9], v[40:41], v[80:81]\n\t"
        "v_pk_fma_f32 v[88:89], v[10:11], v[40:41], v[80:81]\n\t"
        "v_pk_fma_f32 v[74:75], v[8:9], v[42:43], v[82:83]\n\t"
        "v_pk_fma_f32 v[90:91], v[10:11], v[42:43], v[82:83]\n\t"
        "v_pk_fma_f32 v[76:77], v[8:9], v[44:45], v[84:85]\n\t"
        "v_pk_fma_f32 v[92:93], v[10:11], v[44:45], v[84:85]\n\t"
        "v_pk_fma_f32 v[78:79], v[8:9], v[46:47], v[86:87]\n\t"
        "v_pk_fma_f32 v[94:95], v[10:11], v[46:47], v[86:87]\n\t"
        "v_max_f32 v72, 0, v72\n\t" "v_max_f32 v88, 0, v88\n\t"
        "v_max_f32 v73, 0, v73\n\t" "v_max_f32 v89, 0, v89\n\t"
        "v_max_f32 v74, 0, v74\n\t" "v_max_f32 v90, 0, v90\n\t"
        "v_max_f32 v75, 0, v75\n\t" "v_max_f32 v91, 0, v91\n\t"
        "v_max_f32 v76, 0, v76\n\t" "v_max_f32 v92, 0, v92\n\t"
        "v_max_f32 v77, 0, v77\n\t" "v_max_f32 v93, 0, v93\n\t"
        "v_max_f32 v78, 0, v78\n\t" "v_max_f32 v94, 0, v94\n\t"
        "v_max_f32 v79, 0, v79\n\t" "v_max_f32 v95, 0, v95\n\t"
        // su dots: A bank v[16:23], B bank v[24:31]
        "v_pk_mul_f32 v[16:17], v[64:65], v[72:73]\n\t"
        "v_pk_mul_f32 v[24:25], v[96:97], v[88:89]\n\t"
        "v_pk_mul_f32 v[18:19], v[66:67], v[74:75]\n\t"
        "v_pk_mul_f32 v[26:27], v[98:99], v[90:91]\n\t"
        "v_pk_mul_f32 v[20:21], v[68:69], v[76:77]\n\t"
        "v_pk_mul_f32 v[28:29], v[100:101], v[92:93]\n\t"
        "v_pk_mul_f32 v[22:23], v[70:71], v[78:79]\n\t"
        "v_pk_mul_f32 v[30:31], v[102:103], v[94:95]\n\t"
        "v_pk_add_f32 v[16:17], v[16:17], v[18:19]\n\t"
        "v_pk_add_f32 v[24:25], v[24:25], v[26:27]\n\t"
        "v_pk_add_f32 v[20:21], v[20:21], v[22:23]\n\t"
        "v_pk_add_f32 v[28:29], v[28:29], v[30:31]\n\t"
        "v_pk_add_f32 v[16:17], v[16:17], v[20:21]\n\t"
        "v_pk_add_f32 v[24:25], v[24:25], v[28:29]\n\t"
        "v_add_f32 v16, v16, v17\n\t"               // suA lane-partial
        "v_add_f32 v24, v24, v25\n\t"               // suB lane-partial
        // sh dots: A temps [18:23]+[36:37], B temps [26:31]+[38:39]
        "v_pk_mul_f32 v[18:19], v[72:73], v[72:73]\n\t"
        "v_pk_mul_f32 v[26:27], v[88:89], v[88:89]\n\t"
        "v_pk_mul_f32 v[20:21], v[74:75], v[74:75]\n\t"
        "v_pk_mul_f32 v[28:29], v[90:91], v[90:91]\n\t"
        "v_pk_mul_f32 v[22:23], v[76:77], v[76:77]\n\t"
        "v_pk_mul_f32 v[30:31], v[92:93], v[92:93]\n\t"
        "v_pk_mul_f32 v[36:37], v[78:79], v[78:79]\n\t"
        "v_pk_mul_f32 v[38:39], v[94:95], v[94:95]\n\t"
        "v_pk_add_f32 v[18:19], v[18:19], v[20:21]\n\t"
        "v_pk_add_f32 v[26:27], v[26:27], v[28:29]\n\t"
        "v_pk_add_f32 v[22:23], v[22:23], v[36:37]\n\t"
        "v_pk_add_f32 v[30:31], v[30:31], v[38:39]\n\t"
        "v_pk_add_f32 v[18:19], v[18:19], v[22:23]\n\t"
        "v_pk_add_f32 v[26:27], v[26:27], v[30:31]\n\t"
        "v_add_f32 v18, v18, v19\n\t"               // shA lane-partial
        "v_add_f32 v26, v26, v27\n\t"               // shB lane-partial
        "s_nop 1\n\t"
        // DPP reduce to lane 63: 4 chains (v16 suA, v18 shA, v24 suB, v26 shB)
        "v_mov_b32_dpp v32, v16 row_shr:1 row_mask:0xf bank_mask:0xf\n\t"
        "v_mov_b32_dpp v33, v18 row_shr:1 row_mask:0xf bank_mask:0xf\n\t"
        "v_mov_b32_dpp v34, v24 row_shr:1 row_mask:0xf bank_mask:0xf\n\t"
        "v_mov_b32_dpp v35, v26 row_shr:1 row_mask:0xf bank_mask:0xf\n\t"
        "v_add_f32 v16, v16, v32\n\t"
        "v_add_f32 v18, v18, v33\n\t"
        "v_add_f32 v24, v24, v34\n\t"
        "v_add_f32 v26, v26, v35\n\t"
        "v_mov_b32_dpp v32, v16 row_shr:2 row_mask:0xf bank_mask:0xf\n\t"
        "v_mov_b32_dpp v33, v18 row_shr:2 row_mask:0xf bank_mask:0xf\n\t"
        "v_mov_b32_dpp v34, v24 row_shr:2 row_mask:0xf bank_mask:0xf\n\t"
        "v_mov_b32_dpp v35, v26 row_shr:2 row_mask:0xf bank_mask:0xf\n\t"
        "v_add_f32 v16, v16, v32\n\t"
        "v_add_f32 v18, v18, v33\n\t"
        "v_add_f32 v24, v24, v34\n\t"
        "v_add_f32 v26, v26, v35\n\t"
        "v_mov_b32_dpp v32, v16 row_shr:4 row_mask:0xf bank_mask:0xf\n\t"
        "v_mov_b32_dpp v33, v18 row_shr:4 row_mask:0xf bank_mask:0xf\n\t"
        "v_mov_b32_dpp v34, v24 row_shr:4 row_mask:0xf bank_mask:0xf\n\t"
        "v_mov_b32_dpp v35, v26 row_shr:4 row_mask:0xf bank_mask:0xf\n\t"
        "v_add_f32 v16, v16, v32\n\t"
        "v_add_f32 v18, v18, v33\n\t"
        "v_add_f32 v24, v24, v34\n\t"
        "v_add_f32 v26, v26, v35\n\t"
        "v_mov_b32_dpp v32, v16 row_shr:8 row_mask:0xf bank_mask:0xf\n\t"
        "v_mov_b32_dpp v33, v18 row_shr:8 row_mask:0xf bank_mask:0xf\n\t"
        "v_mov_b32_dpp v34, v24 row_shr:8 row_mask:0xf bank_mask:0xf\n\t"
        "v_mov_b32_dpp v35, v26 row_shr:8 row_mask:0xf bank_mask:0xf\n\t"
        "v_add_f32 v16, v16, v32\n\t"
        "v_add_f32 v18, v18, v33\n\t"
        "v_add_f32 v24, v24, v34\n\t"
        "v_add_f32 v26, v26, v35\n\t"
        "v_mov_b32_dpp v32, v16 row_bcast:15 row_mask:0xf bank_mask:0xf\n\t"
        "v_mov_b32_dpp v33, v18 row_bcast:15 row_mask:0xf bank_mask:0xf\n\t"
        "v_mov_b32_dpp v34, v24 row_bcast:15 row_mask:0xf bank_mask:0xf\n\t"
        "v_mov_b32_dpp v35, v26 row_bcast:15 row_mask:0xf bank_mask:0xf\n\t"
        "v_add_f32 v16, v16, v32\n\t"
        "v_add_f32 v18, v18, v33\n\t"
        "v_add_f32 v24, v24, v34\n\t"
        "v_add_f32 v26, v26, v35\n\t"
        "v_mov_b32_dpp v32, v16 row_bcast:31 row_mask:0xf bank_mask:0xf\n\t"
        "v_mov_b32_dpp v33, v18 row_bcast:31 row_mask:0xf bank_mask:0xf\n\t"
        "v_mov_b32_dpp v34, v24 row_bcast:31 row_mask:0xf bank_mask:0xf\n\t"
        "v_mov_b32_dpp v35, v26 row_bcast:31 row_mask:0xf bank_mask:0xf\n\t"
        "v_add_f32 v16, v16, v32\n\t"
        "v_add_f32 v18, v18, v33\n\t"
        "v_add_f32 v24, v24, v34\n\t"
        "v_add_f32 v26, v26, v35\n\t"
        "s_nop 1\n\t"
        // publish quad {suA,shA,suB,shB} from lane 63
        "v_mov_b32 v36, v16\n\t"
        "v_mov_b32 v37, v18\n\t"
        "v_mov_b32 v38, v24\n\t"
        "v_mov_b32 v39, v26\n\t"
        "s_and_saveexec_b64 s[72:73], s[74:75]\n\t"
        "ds_write_b128 v4, v[36:39]\n\t"
        "s_mov_b64 exec, s[72:73]\n\t"
        "s_waitcnt lgkmcnt(0)\n\t"                  // only this ds_write
        "s_barrier\n\t"
        "ds_read_b128 v[16:19], v5\n\t"             // w0 {suA,shA,suB,shB}
        "ds_read_b128 v[20:23], v5 offset:16\n\t"   // w1
        "ds_read_b128 v[24:27], v5 offset:32\n\t"   // w2
        "ds_read_b128 v[28:31], v5 offset:48\n\t"   // w3
        // ---- ds_read shadow: shared-state updates for t+1 ----
        "v_mul_f32 v104, %[omq], v104\n\t"          // qlp_{t+1}
        "v_fmac_f32 v104, s71, %[otq]\n\t"          //  (B.q)
        "v_mul_f32 v12, v104, %[oq]\n\t"
        "v_mov_b32 v13, v12\n\t"
        "v_pk_fma_f32 v[80:81], v[12:13], v[48:49], v[56:57]\n\t"  // hb_{t+1}
        "v_pk_fma_f32 v[82:83], v[12:13], v[50:51], v[58:59]\n\t"
        "v_pk_fma_f32 v[84:85], v[12:13], v[52:53], v[60:61]\n\t"
        "v_pk_fma_f32 v[86:87], v[12:13], v[54:55], v[62:63]\n\t"
        "v_mul_f32 v105, %[omy], v105\n\t"          // ylp_t
        "v_fmac_f32 v105, s66, %[oty]\n\t"          //  (A.y)
        "v_add_f32 v112, s54, v105\n\t"             // preA = ylp_t + nzA_{t+1}
        "v_add_f32 v113, s55, v105\n\t"             // preB
        "v_mul_f32 v114, %[olr], v108\n\t"          // elpreA = lr0*lrmA
        "v_mul_f32 v115, %[olr], v109\n\t"          // elpreB
        "v_xor_b32 v4, 64, v4\n\t"                  // parity toggles (64B)
        "v_xor_b32 v5, 64, v5\n\t"
        "s_mov_b32 s66, s70\n\t"                    // rotate A <- B
        "s_mov_b32 s67, s71\n\t"
        "s_mov_b32 s68, s54\n\t"
        "s_mov_b32 s69, s55\n\t"
        "s_mov_b32 s70, s50\n\t"                    // rotate B <- C
        "s_mov_b32 s71, s51\n\t"
        "s_mov_b32 s54, s52\n\t"
        "s_mov_b32 s55, s53\n\t"
        "s_add_u32 s60, s60, 1\n\t"
        // ---- end shadow ----
        "s_waitcnt lgkmcnt(0)\n\t"                  // only the 4 ds_reads
        "v_pk_add_f32 v[16:17], v[16:17], v[20:21]\n\t"
        "v_pk_add_f32 v[18:19], v[18:19], v[22:23]\n\t"
        "v_pk_add_f32 v[24:25], v[24:25], v[28:29]\n\t"
        "v_pk_add_f32 v[26:27], v[26:27], v[30:31]\n\t"
        "v_pk_add_f32 v[16:17], v[16:17], v[24:25]\n\t"  // {suA_t, shA_t}
        "v_pk_add_f32 v[18:19], v[18:19], v[26:27]\n\t"  // {suB_t, shB_t}
        // issue C <- scalars(t+3): earliest post-drain point, max distance
        "s_load_dword s50, %[pys], s61\n\t"
        "s_load_dword s51, %[pqs], s61\n\t"
        "s_load_dwordx2 s[52:53], %[pnz], s62\n\t"
        "s_add_u32 s61, s61, 4\n\t"
        "s_min_u32 s61, s61, 0x3fc\n\t"
        "s_add_u32 s62, s62, 0x800\n\t"
        "s_min_u32 s62, s62, 0x7f800\n\t"
        // u, stores (pair), x'
        "v_mul_f32 v106, v16, v110\n\t"             // uA = sp*suA
        "v_mul_f32 v107, v18, v110\n\t"             // uB
        "v_mul_f32 v36, %[oos], v106\n\t"
        "v_mul_f32 v37, %[oos], v107\n\t"
        "s_and_saveexec_b64 s[72:73], s[76:77]\n\t"
        "global_store_dwordx2 v6, v[36:37], %[pou]\n\t"
        "s_mov_b64 exec, s[72:73]\n\t"
        "v_add_u32 v6, 0x800, v6\n\t"
        "v_fma_f32 v8, %[oum], v106, v112\n\t"      // xA'
        "v_mov_b32 v9, v8\n\t"
        "v_fma_f32 v10, %[oum], v107, v113\n\t"     // xB'
        "v_mov_b32 v11, v10\n\t"
        // e, el, cc (A: v38/v[14:15], B: v39/v[34:35])
        "v_sub_f32 v38, v105, v106\n\t"
        "v_sub_f32 v39, v105, v107\n\t"
        "v_mul_f32 v38, v114, v38\n\t"              // elA
        "v_mul_f32 v39, v115, v39\n\t"              // elB
        "v_mul_f32 v14, v38, v111\n\t"              // cA = elA*rsp
        "v_mov_b32 v15, v14\n\t"
        "v_mul_f32 v34, v39, v111\n\t"              // cB
        "v_mov_b32 v35, v34\n\t"
        // norm chains interleaved with v-updates (fill sqrt/exp latency)
        "v_mul_f32 v30, v38, v38\n\t"
        "v_mul_f32 v31, v39, v39\n\t"
        "v_mul_f32 v30, v17, v30\n\t"               // *shA_t
        "v_mul_f32 v31, v19, v31\n\t"               // *shB_t
        "v_add_f32 v30, 0x38d1b717, v30\n\t"        // + 1e-4f
        "v_add_f32 v31, 0x38d1b717, v31\n\t"
        "v_sqrt_f32 v30, v30\n\t"
        "v_sqrt_f32 v31, v31\n\t"
        "v_pk_fma_f32 v[64:65], v[14:15], v[72:73], v[64:65]\n\t"
        "v_pk_fma_f32 v[96:97], v[34:35], v[88:89], v[96:97]\n\t"
        "v_pk_fma_f32 v[66:67], v[14:15], v[74:75], v[66:67]\n\t"
        "v_pk_fma_f32 v[98:99], v[34:35], v[90:91], v[98:99]\n\t"
        "v_mul_f32 v30, %[ond], v30\n\t"
        "v_mul_f32 v31, %[ond], v31\n\t"
        "v_exp_f32 v30, v30\n\t"
        "v_exp_f32 v31, v31\n\t"
        "v_pk_fma_f32 v[68:69], v[14:15], v[76:77], v[68:69]\n\t"
        "v_pk_fma_f32 v[100:101], v[34:35], v[92:93], v[100:101]\n\t"
        "v_pk_fma_f32 v[70:71], v[14:15], v[78:79], v[70:71]\n\t"
        "v_pk_fma_f32 v[102:103], v[34:35], v[94:95], v[102:103]\n\t"
        "v_mul_f32 v110, %[owd], v110\n\t"          // sp *= wd
        "v_mul_f32 v111, %[orw], v111\n\t"          // rsp *= rwd
        "v_mul_f32 v108, v108, v30\n\t"             // lrmA *= exp2(...)
        "v_mul_f32 v109, v109, v31\n\t"             // lrmB
        "s_cmp_lt_u32 s60, 0x100\n\t"
        "s_cbranch_scc1 Lelbo5\n\t"
        "s_waitcnt vmcnt(0) lgkmcnt(0)\n\t"
        :
        : [pys]"s"(ys), [pqs]"s"(qs), [pnz]"s"(nzp), [pou]"s"(out),
          [pzb]"s"(z_biases), [pwi]"s"(w_in), [pwq]"s"(w_inq),
          [vtid]"v"(tid), [ovo]"v"(ovo),
          [osg]"v"(sigb), [otq]"v"(tauq), [omq]"v"(omtq),
          [oty]"v"(tauy), [omy]"v"(omty), [oq]"v"(qscale),
          [oum]"v"(ufsm1), [olr]"v"(lr0), [owd]"v"(wd), [orw]"v"(rwd),
          [oos]"v"(oscale), [ond]"v"(nld2)
        : "memory", "scc", "vcc",
          "s50","s51","s52","s53","s54","s55",
          "s60","s61","s62","s66","s67","s68","s69","s70","s71",
          "s72","s73","s74","s75","s76","s77",
          "v1","v2","v3","v4","v5","v6","v7","v8","v9","v10","v11",
          "v12","v13","v14","v15","v16","v17","v18","v19","v20","v21",
          "v22","v23","v24","v25","v26","v27","v28","v29","v30","v31",
          "v32","v33","v34","v35","v36","v37","v38","v39","v40","v41",
          "v42","v43","v44","v45","v46","v47","v48","v49","v50","v51",
          "v52","v53","v54","v55","v56","v57","v58","v59","v60","v61",
          "v62","v63","v64","v65","v66","v67","v68","v69","v70","v71",
          "v72","v73","v74","v75","v76","v77","v78","v79","v80","v81",
          "v82","v83","v84","v85","v86","v87","v88","v89","v90","v91",
          "v92","v93","v94","v95","v96","v97","v98","v99","v100","v101",
          "v102","v103","v104","v105","v106","v107","v108","v109","v110",
          "v111","v112","v113","v114","v115"
    );
}

extern "C" void kernel_launch(void* const* d_in, const int* in_sizes, int n_in,
                              void* d_out, int out_size, void* d_ws, size_t ws_size,
                              hipStream_t stream) {
    (void)in_sizes; (void)n_in; (void)d_ws; (void)ws_size; (void)out_size;
    const float* noises   = (const float*)d_in[0];
    const float* ys       = (const float*)d_in[1];
    const float* qs       = (const float*)d_in[2];
    const float* z_biases = (const float*)d_in[3];
    const float* w_in     = (const float*)d_in[4];
    const float* w_inq    = (const float*)d_in[5];
    const float* llr      = (const float*)d_in[6];
    const float* llrd     = (const float*)d_in[7];
    const float* sigb     = (const float*)d_in[8];
    const float* oscale   = (const float*)d_in[9];
    const float* ufs      = (const float*)d_in[10];
    const float* lwd      = (const float*)d_in[11];
    const float* qscale   = (const float*)d_in[12];
    const float* tauq     = (const float*)d_in[13];
    const float* tauy     = (const float*)d_in[14];
    float* out = (float*)d_out;

    // 128 B dynamic LDS: keeps raw ds addresses 0..127 valid even if the
    // compiler were to drop the static red_lds allocation.
    hipLaunchKernelGGL(legacy_elbo_scan_kernel, dim3(BS / 2), dim3(BLOCK), 128,
                       stream,
                       noises, ys, qs, z_biases, w_in, w_inq,
                       llr, llrd, sigb, oscale, ufs, lwd, qscale, tauq, tauy,
                       out);
}

// Round 13
// 196.005 us; speedup vs baseline: 1.0501x; 1.0501x over previous
//
#include <hip/hip_runtime.h>
#include <math.h>
#include <stdint.h>

#define T_STEPS 256
#define BS      512
#define N       2048
#define BLOCK   256               // 4 waves per batch element, EPT=8
#define FUDGE   1e-4f

// R20: R17 (121us, measured best) + ONLY the critical-path shortening that
// R18 bundled with two identified regressions (vector-scalar plumbing; 4x
// duplicate stores). Changes vs R17:
//  - hb=cb+qsc*cq (8 pk_fma) + qlp/qsc moved into the ds_read shadow
//  - pre=ylp_t+nz_{t+1}, elpre=lr0*lrm precomputed in shadow
//  - x_{t+1}=fma(ufs-1,u,pre): loop top starts directly with h
//  - dots via pk_mul + add-tree (no zero-init, 2 fewer dep levels)
// Kept from R17: s_load scalar triple-buffer (A/B/C), single tid0 store,
// lane-63 ds_write2 + 1 barrier + parity LDS, DPP reduce with s_nop spacing.
__global__ __launch_bounds__(BLOCK, 2)
void legacy_elbo_scan_kernel(
    const float* __restrict__ noises,   // [T, BS]
    const float* __restrict__ ys,       // [T]
    const float* __restrict__ qs,       // [T]
    const float* __restrict__ z_biases, // [N]
    const float* __restrict__ w_in,     // [N]
    const float* __restrict__ w_inq,    // [N]
    const float* __restrict__ p_llr,
    const float* __restrict__ p_llrd,
    const float* __restrict__ p_sigb,
    const float* __restrict__ p_oscale,
    const float* __restrict__ p_ufs,
    const float* __restrict__ p_lwd,
    const float* __restrict__ p_qscale,
    const float* __restrict__ p_tauq,
    const float* __restrict__ p_tauy,
    float* __restrict__ out)            // [T, BS]
{
    const int tid = threadIdx.x;
    const int blk = blockIdx.x;

    __shared__ float red_lds[16];       // [parity 2][wave 4][su,sh] = 64 B
    if (tid < 16) red_lds[tid] = 0.0f;  // keep the allocation live, offset 0
    __syncthreads();

    const float sigb    = p_sigb[0];
    const float lr0     = expf(p_llr[0]);
    const float lr_decay= expf(p_llrd[0]);
    const float wd      = expf(p_lwd[0]);
    const float rwd     = 1.0f / wd;
    const float tauq    = 1.0f + log1pf(expf(p_tauq[0]));
    const float tauy    = 1.0f + log1pf(expf(p_tauy[0]));
    const float omtq    = 1.0f - tauq;
    const float omty    = 1.0f - tauy;
    const float qscale  = p_qscale[0];
    const float ufsm1   = p_ufs[0] - 1.0f;   // x' = pre + (ufs-1)*u
    const float oscale  = p_oscale[0];
    // __expf(x) == exp2(x * log2(e)); fold -lr_decay into the multiplier.
    const float nld2    = -lr_decay * 1.4426950408889634f;

    const float* nzp = noises + blk;    // uniform: per-block noise column base
    const int    ovo = blk * 4;         // byte offset of out[0*BS+blk]

    asm volatile(
        // -------- init: ids, masks, LDS addrs, coeff + scalar loads ---------
        "v_lshrrev_b32 v3, 6, %[vtid]\n\t"          // wid (0..3)
        "v_lshlrev_b32 v4, 3, v3\n\t"               // ds write addr = wid*8
        "v_and_b32 v7, 63, %[vtid]\n\t"             // lane id
        "v_cmp_eq_u32 vcc, 63, v7\n\t"              // lane-63 mask
        "s_mov_b64 s[74:75], vcc\n\t"
        "v_cmp_eq_u32 vcc, 0, %[vtid]\n\t"          // tid==0 mask (wave0 only)
        "s_mov_b64 s[76:77], vcc\n\t"
        "v_mov_b32 v5, 0\n\t"                       // ds read base (parity 0)
        "v_lshlrev_b32 v1, 4, %[vtid]\n\t"          // tid*16 bytes
        "v_add_u32 v2, 0x1000, v1\n\t"              // +4096 for chunk 1
        "global_load_dwordx4 v[40:43], v1, %[pzb]\n\t"   // cb
        "global_load_dwordx4 v[44:47], v2, %[pzb]\n\t"
        "global_load_dwordx4 v[48:51], v1, %[pwi]\n\t"   // cw
        "global_load_dwordx4 v[52:55], v2, %[pwi]\n\t"
        "global_load_dwordx4 v[56:59], v1, %[pwq]\n\t"   // cq
        "global_load_dwordx4 v[60:63], v2, %[pwq]\n\t"
        // scalar triple buffer: A=t0 (s66-68), B=t1 (s69-71), C=t2 (s50-52)
        "s_mov_b32 s61, 12\n\t"                     // y/q byte off for t3
        "s_mov_b32 s62, 0x1800\n\t"                 // nz byte off for t3
        "s_load_dword s66, %[pys], 0x0\n\t"
        "s_load_dword s67, %[pqs], 0x0\n\t"
        "s_load_dword s68, %[pnz], 0x0\n\t"
        "s_load_dword s69, %[pys], 0x4\n\t"
        "s_load_dword s70, %[pqs], 0x4\n\t"
        "s_load_dword s71, %[pnz], 0x800\n\t"
        "s_load_dword s50, %[pys], 0x8\n\t"
        "s_load_dword s51, %[pqs], 0x8\n\t"
        "s_load_dword s52, %[pnz], 0x1000\n\t"
        "s_waitcnt vmcnt(0) lgkmcnt(0)\n\t"
        // scale biases by sigma_b
        "v_mul_f32 v40, %[osg], v40\n\t"  "v_mul_f32 v41, %[osg], v41\n\t"
        "v_mul_f32 v42, %[osg], v42\n\t"  "v_mul_f32 v43, %[osg], v43\n\t"
        "v_mul_f32 v44, %[osg], v44\n\t"  "v_mul_f32 v45, %[osg], v45\n\t"
        "v_mul_f32 v46, %[osg], v46\n\t"  "v_mul_f32 v47, %[osg], v47\n\t"
        // zero w_out state v64..v71
        "v_mov_b32 v64, 0\n\t" "v_mov_b32 v65, 0\n\t" "v_mov_b32 v66, 0\n\t" "v_mov_b32 v67, 0\n\t"
        "v_mov_b32 v68, 0\n\t" "v_mov_b32 v69, 0\n\t" "v_mov_b32 v70, 0\n\t" "v_mov_b32 v71, 0\n\t"
        // state: qlp v20, ylp v21, u v22, lrm v24, sp v25, rsp v26, elpre v27
        "v_mov_b32 v21, 0\n\t" "v_mov_b32 v22, 0\n\t"
        "v_mov_b32 v24, 1.0\n\t" "v_mov_b32 v25, 1.0\n\t" "v_mov_b32 v26, 1.0\n\t"
        "v_mov_b32 v27, %[olr]\n\t"                 // elpre0 = lr0*1
        "v_mov_b32 v6, %[ovo]\n\t"                  // out byte-offset
        "s_mov_b32 s60, 0\n\t"                      // t
        // qlp0 = tauq*q0 ; qsc pair v[10:11]
        "v_mul_f32 v20, s67, %[otq]\n\t"
        "v_mul_f32 v10, %[oq], v20\n\t"
        "v_mov_b32 v11, v10\n\t"
        // hb0 = cb + qsc0*cq  (v80-87)
        "v_pk_fma_f32 v[80:81], v[10:11], v[56:57], v[40:41]\n\t"
        "v_pk_fma_f32 v[82:83], v[10:11], v[58:59], v[42:43]\n\t"
        "v_pk_fma_f32 v[84:85], v[10:11], v[60:61], v[44:45]\n\t"
        "v_pk_fma_f32 v[86:87], v[10:11], v[62:63], v[46:47]\n\t"
        // x0 = nz0 (u=e=0) ; pair v[8:9]
        "v_mov_b32 v8, s68\n\t"
        "v_mov_b32 v9, v8\n\t"
        // ---------------- main scan loop ------------------------------------
        "Lelbo6:\n\t"
        // h = relu(hb + x*cw)   (x and hb precomputed last iteration)
        "v_pk_fma_f32 v[72:73], v[8:9], v[48:49], v[80:81]\n\t"
        "v_pk_fma_f32 v[74:75], v[8:9], v[50:51], v[82:83]\n\t"
        "v_pk_fma_f32 v[76:77], v[8:9], v[52:53], v[84:85]\n\t"
        "v_pk_fma_f32 v[78:79], v[8:9], v[54:55], v[86:87]\n\t"
        "v_max_f32 v72, 0, v72\n\t" "v_max_f32 v73, 0, v73\n\t"
        "v_max_f32 v74, 0, v74\n\t" "v_max_f32 v75, 0, v75\n\t"
        "v_max_f32 v76, 0, v76\n\t" "v_max_f32 v77, 0, v77\n\t"
        "v_max_f32 v78, 0, v78\n\t" "v_max_f32 v79, 0, v79\n\t"
        // su = v.h (v12-19), sh = h.h (v88-95): pk_mul + add tree
        "v_pk_mul_f32 v[12:13], v[64:65], v[72:73]\n\t"
        "v_pk_mul_f32 v[14:15], v[66:67], v[74:75]\n\t"
        "v_pk_mul_f32 v[16:17], v[68:69], v[76:77]\n\t"
        "v_pk_mul_f32 v[18:19], v[70:71], v[78:79]\n\t"
        "v_pk_mul_f32 v[88:89], v[72:73], v[72:73]\n\t"
        "v_pk_mul_f32 v[90:91], v[74:75], v[74:75]\n\t"
        "v_pk_mul_f32 v[92:93], v[76:77], v[76:77]\n\t"
        "v_pk_mul_f32 v[94:95], v[78:79], v[78:79]\n\t"
        "v_pk_add_f32 v[12:13], v[12:13], v[14:15]\n\t"
        "v_pk_add_f32 v[16:17], v[16:17], v[18:19]\n\t"
        "v_pk_add_f32 v[88:89], v[88:89], v[90:91]\n\t"
        "v_pk_add_f32 v[92:93], v[92:93], v[94:95]\n\t"
        "v_pk_add_f32 v[12:13], v[12:13], v[16:17]\n\t"
        "v_pk_add_f32 v[88:89], v[88:89], v[92:93]\n\t"
        "v_add_f32 v12, v12, v13\n\t"               // su lane-partial
        "v_add_f32 v16, v88, v89\n\t"               // sh lane-partial
        // wave reduce to lane 63 (DPP), su v12/tmp v30, sh v16/tmp v31
        "s_nop 1\n\t"
        "v_mov_b32_dpp v30, v12 row_shr:1 row_mask:0xf bank_mask:0xf\n\t"
        "v_mov_b32_dpp v31, v16 row_shr:1 row_mask:0xf bank_mask:0xf\n\t"
        "v_add_f32 v12, v12, v30\n\t"
        "v_add_f32 v16, v16, v31\n\t"
        "s_nop 0\n\t"
        "v_mov_b32_dpp v30, v12 row_shr:2 row_mask:0xf bank_mask:0xf\n\t"
        "v_mov_b32_dpp v31, v16 row_shr:2 row_mask:0xf bank_mask:0xf\n\t"
        "v_add_f32 v12, v12, v30\n\t"
        "v_add_f32 v16, v16, v31\n\t"
        "s_nop 0\n\t"
        "v_mov_b32_dpp v30, v12 row_shr:4 row_mask:0xf bank_mask:0xf\n\t"
        "v_mov_b32_dpp v31, v16 row_shr:4 row_mask:0xf bank_mask:0xf\n\t"
        "v_add_f32 v12, v12, v30\n\t"
        "v_add_f32 v16, v16, v31\n\t"
        "s_nop 0\n\t"
        "v_mov_b32_dpp v30, v12 row_shr:8 row_mask:0xf bank_mask:0xf\n\t"
        "v_mov_b32_dpp v31, v16 row_shr:8 row_mask:0xf bank_mask:0xf\n\t"
        "v_add_f32 v12, v12, v30\n\t"
        "v_add_f32 v16, v16, v31\n\t"
        "s_nop 0\n\t"
        "v_mov_b32_dpp v30, v12 row_bcast:15 row_mask:0xf bank_mask:0xf\n\t"
        "v_mov_b32_dpp v31, v16 row_bcast:15 row_mask:0xf bank_mask:0xf\n\t"
        "v_add_f32 v12, v12, v30\n\t"
        "v_add_f32 v16, v16, v31\n\t"
        "s_nop 0\n\t"
        "v_mov_b32_dpp v30, v12 row_bcast:31 row_mask:0xf bank_mask:0xf\n\t"
        "v_mov_b32_dpp v31, v16 row_bcast:31 row_mask:0xf bank_mask:0xf\n\t"
        "v_add_f32 v12, v12, v30\n\t"
        "v_add_f32 v16, v16, v31\n\t"
        "s_nop 1\n\t"
        // lane 63 publishes {su, sh}; barrier; issue combine reads
        "s_and_saveexec_b64 s[72:73], s[74:75]\n\t"
        "ds_write2_b32 v4, v12, v16 offset0:0 offset1:1\n\t"
        "s_mov_b64 exec, s[72:73]\n\t"
        "s_waitcnt lgkmcnt(0)\n\t"                  // only the ds_write
        "s_barrier\n\t"
        "ds_read_b128 v[32:35], v5\n\t"
        "ds_read_b128 v[36:39], v5 offset:16\n\t"
        // ---- ds_read shadow: all t+1 prep not needing su/sh ----
        "v_mul_f32 v20, %[omq], v20\n\t"            // qlp_{t+1}
        "v_fmac_f32 v20, s70, %[otq]\n\t"           //  (B.q)
        "v_mul_f32 v10, %[oq], v20\n\t"             // qsc pair
        "v_mov_b32 v11, v10\n\t"
        "v_pk_fma_f32 v[80:81], v[10:11], v[56:57], v[40:41]\n\t"  // hb_{t+1}
        "v_pk_fma_f32 v[82:83], v[10:11], v[58:59], v[42:43]\n\t"
        "v_pk_fma_f32 v[84:85], v[10:11], v[60:61], v[44:45]\n\t"
        "v_pk_fma_f32 v[86:87], v[10:11], v[62:63], v[46:47]\n\t"
        "v_mul_f32 v21, %[omy], v21\n\t"            // ylp_t
        "v_fmac_f32 v21, s66, %[oty]\n\t"           //  (A.y)
        "v_add_f32 v1, s71, v21\n\t"                // pre = ylp_t + nz_{t+1}
        "v_mul_f32 v27, %[olr], v24\n\t"            // elpre = lr0*lrm_t
        "v_xor_b32 v4, 32, v4\n\t"                  // parity toggles
        "v_xor_b32 v5, 32, v5\n\t"
        "s_mov_b32 s66, s69\n\t"                    // rotate y: A <- B
        "s_mov_b32 s69, s50\n\t"                    //          B <- C
        "s_mov_b32 s70, s51\n\t"                    // rotate q: B <- C
        "s_mov_b32 s71, s52\n\t"                    // rotate nz: B <- C
        "s_add_u32 s60, s60, 1\n\t"
        // ---- end shadow ----
        "s_waitcnt lgkmcnt(0)\n\t"                  // only the 2 ds_reads
        "v_pk_add_f32 v[32:33], v[32:33], v[34:35]\n\t"
        "v_pk_add_f32 v[36:37], v[36:37], v[38:39]\n\t"
        "v_pk_add_f32 v[32:33], v[32:33], v[36:37]\n\t"   // su v32, sh v33
        // u ; store (tid0 only) ; x_{t+1}
        "v_mul_f32 v22, v25, v32\n\t"
        "v_mul_f32 v30, %[oos], v22\n\t"
        "s_and_saveexec_b64 s[72:73], s[76:77]\n\t"
        "global_store_dword v6, v30, %[pou]\n\t"
        "s_mov_b64 exec, s[72:73]\n\t"
        "v_add_u32 v6, 0x800, v6\n\t"               // next row (+BS*4)
        "v_fma_f32 v8, %[oum], v22, v1\n\t"         // x' = pre + (ufs-1)*u
        "v_mov_b32 v9, v8\n\t"
        // e, el, c
        "v_sub_f32 v23, v21, v22\n\t"               // e = ylp - u
        "v_mul_f32 v31, v27, v23\n\t"               // el = elpre*e
        "v_mul_f32 v28, v31, v26\n\t"               // c = el*rsp
        "v_mov_b32 v29, v28\n\t"
        // issue C <- scalars(t+3) AFTER the last lgkm drain of this step
        "s_load_dword s50, %[pys], s61\n\t"
        "s_load_dword s51, %[pqs], s61\n\t"
        "s_load_dword s52, %[pnz], s62\n\t"
        "s_add_u32 s61, s61, 4\n\t"
        "s_min_u32 s61, s61, 0x3fc\n\t"
        "s_add_u32 s62, s62, 0x800\n\t"
        "s_min_u32 s62, s62, 0x7f800\n\t"
        // norm chain with v-update filling sqrt latency
        "v_mul_f32 v30, v31, v31\n\t"               // el^2
        "v_mul_f32 v30, v33, v30\n\t"               // *sh_t
        "v_add_f32 v30, 0x38d1b717, v30\n\t"        // + 1e-4f
        "v_sqrt_f32 v30, v30\n\t"
        "v_pk_fma_f32 v[64:65], v[28:29], v[72:73], v[64:65]\n\t"
        "v_pk_fma_f32 v[66:67], v[28:29], v[74:75], v[66:67]\n\t"
        "v_pk_fma_f32 v[68:69], v[28:29], v[76:77], v[68:69]\n\t"
        "v_pk_fma_f32 v[70:71], v[28:29], v[78:79], v[70:71]\n\t"
        "v_mul_f32 v30, %[ond], v30\n\t"
        "v_exp_f32 v30, v30\n\t"
        "s_nop 1\n\t"
        "v_mul_f32 v25, %[owd], v25\n\t"            // sp *= wd
        "v_mul_f32 v26, %[orw], v26\n\t"            // rsp *= rwd
        "v_mul_f32 v24, v24, v30\n\t"               // lrm *= exp2(...)
        "s_cmp_lt_u32 s60, 0x100\n\t"
        "s_cbranch_scc1 Lelbo6\n\t"
        "s_waitcnt vmcnt(0) lgkmcnt(0)\n\t"         // drain stores
        :
        : [pys]"s"(ys), [pqs]"s"(qs), [pnz]"s"(nzp), [pou]"s"(out),
          [pzb]"s"(z_biases), [pwi]"s"(w_in), [pwq]"s"(w_inq),
          [vtid]"v"(tid), [ovo]"v"(ovo),
          [osg]"v"(sigb), [otq]"v"(tauq), [omq]"v"(omtq),
          [oty]"v"(tauy), [omy]"v"(omty), [oq]"v"(qscale),
          [oum]"v"(ufsm1), [olr]"v"(lr0), [owd]"v"(wd), [orw]"v"(rwd),
          [oos]"v"(oscale), [ond]"v"(nld2)
        : "memory", "scc", "vcc",
          "s50","s51","s52",
          "s60","s61","s62","s66","s67","s68","s69","s70","s71",
          "s72","s73","s74","s75","s76","s77",
          "v1","v2","v3","v4","v5","v6","v7","v8","v9","v10","v11",
          "v12","v13","v14","v15","v16","v17","v18","v19","v20","v21",
          "v22","v23","v24","v25","v26","v27","v28","v29","v30","v31",
          "v32","v33","v34","v35","v36","v37","v38","v39","v40","v41",
          "v42","v43","v44","v45","v46","v47","v48","v49","v50","v51",
          "v52","v53","v54","v55","v56","v57","v58","v59","v60","v61",
          "v62","v63","v64","v65","v66","v67","v68","v69","v70","v71",
          "v72","v73","v74","v75","v76","v77","v78","v79","v80","v81",
          "v82","v83","v84","v85","v86","v87","v88","v89","v90","v91",
          "v92","v93","v94","v95"
    );
}

extern "C" void kernel_launch(void* const* d_in, const int* in_sizes, int n_in,
                              void* d_out, int out_size, void* d_ws, size_t ws_size,
                              hipStream_t stream) {
    (void)in_sizes; (void)n_in; (void)d_ws; (void)ws_size; (void)out_size;
    const float* noises   = (const float*)d_in[0];
    const float* ys       = (const float*)d_in[1];
    const float* qs       = (const float*)d_in[2];
    const float* z_biases = (const float*)d_in[3];
    const float* w_in     = (const float*)d_in[4];
    const float* w_inq    = (const float*)d_in[5];
    const float* llr      = (const float*)d_in[6];
    const float* llrd     = (const float*)d_in[7];
    const float* sigb     = (const float*)d_in[8];
    const float* oscale   = (const float*)d_in[9];
    const float* ufs      = (const float*)d_in[10];
    const float* lwd      = (const float*)d_in[11];
    const float* qscale   = (const float*)d_in[12];
    const float* tauq     = (const float*)d_in[13];
    const float* tauy     = (const float*)d_in[14];
    float* out = (float*)d_out;

    // 64 B dynamic LDS: keeps raw ds addresses 0..63 valid even if the
    // compiler were to drop the static red_lds allocation.
    hipLaunchKernelGGL(legacy_elbo_scan_kernel, dim3(BS), dim3(BLOCK), 64, stream,
                       noises, ys, qs, z_biases, w_in, w_inq,
                       llr, llrd, sigb, oscale, ufs, lwd, qscale, tauq, tauy,
                       out);
}

// Round 14
// 189.216 us; speedup vs baseline: 1.0878x; 1.0359x over previous
//
#include <hip/hip_runtime.h>
#include <math.h>
#include <stdint.h>

#define T_STEPS 256
#define BS      512
#define N       2048
#define BLOCK   256               // 4 waves per batch element, EPT=8
#define FUDGE   1e-4f

// R21 = R17 verbatim (measured best: 121us, passed). R18/R19/R20 each tested
// one family of improvements (vector scalars, dual-element ILP, hb-in-shadow
// critical path) and ALL regressed to 131-139us. Structural finding: this
// sequential scan is latency/issue-plateau-bound at ~1130 cy/step -- per-step
// DPP reduce (~24 dependent cross-lane ops) + barrier'd LDS exchange
// (~250-400cy) + ~444cy/SIMD VALU issue demand cannot be mutually hidden
// any further in this design space. R17's schedule is the local optimum:
// triple-buffered s_load scalar prefetch (A/B/C, issued 3 steps ahead after
// the last lgkm drain) + ds_read shadow holding only short element-independent
// updates + single tid0 store + parity-LDS single-barrier exchange.
__global__ __launch_bounds__(BLOCK, 2)
void legacy_elbo_scan_kernel(
    const float* __restrict__ noises,   // [T, BS]
    const float* __restrict__ ys,       // [T]
    const float* __restrict__ qs,       // [T]
    const float* __restrict__ z_biases, // [N]
    const float* __restrict__ w_in,     // [N]
    const float* __restrict__ w_inq,    // [N]
    const float* __restrict__ p_llr,
    const float* __restrict__ p_llrd,
    const float* __restrict__ p_sigb,
    const float* __restrict__ p_oscale,
    const float* __restrict__ p_ufs,
    const float* __restrict__ p_lwd,
    const float* __restrict__ p_qscale,
    const float* __restrict__ p_tauq,
    const float* __restrict__ p_tauy,
    float* __restrict__ out)            // [T, BS]
{
    const int tid = threadIdx.x;
    const int blk = blockIdx.x;

    __shared__ float red_lds[16];       // [parity 2][wave 4][su,sh] = 64 B
    if (tid < 16) red_lds[tid] = 0.0f;  // keep the allocation live, offset 0
    __syncthreads();

    const float sigb    = p_sigb[0];
    const float lr0     = expf(p_llr[0]);
    const float lr_decay= expf(p_llrd[0]);
    const float wd      = expf(p_lwd[0]);
    const float rwd     = 1.0f / wd;
    const float tauq    = 1.0f + log1pf(expf(p_tauq[0]));
    const float tauy    = 1.0f + log1pf(expf(p_tauy[0]));
    const float omtq    = 1.0f - tauq;
    const float omty    = 1.0f - tauy;
    const float qscale  = p_qscale[0];
    const float ufs     = p_ufs[0];
    const float oscale  = p_oscale[0];
    // __expf(x) == exp2(x * log2(e)); fold -lr_decay into the multiplier.
    const float nld2    = -lr_decay * 1.4426950408889634f;

    const float* nzp = noises + blk;    // uniform: per-block noise column base
    const int    ovo = blk * 4;         // byte offset of out[0*BS+blk]

    asm volatile(
        // -------- init: ids, masks, LDS addrs, coeff loads -> v40..v63 ------
        "v_lshrrev_b32 v3, 6, %[vtid]\n\t"          // wid (0..3)
        "v_lshlrev_b32 v4, 3, v3\n\t"               // ds write addr = wid*8
        "v_and_b32 v7, 63, %[vtid]\n\t"             // lane id
        "v_cmp_eq_u32 vcc, 63, v7\n\t"              // lane-63 mask
        "s_mov_b64 s[74:75], vcc\n\t"
        "v_cmp_eq_u32 vcc, 0, %[vtid]\n\t"          // tid==0 mask (wave0 only)
        "s_mov_b64 s[76:77], vcc\n\t"
        "v_mov_b32 v5, 0\n\t"                       // ds read base (parity 0)
        "v_lshlrev_b32 v1, 4, %[vtid]\n\t"          // tid*16 bytes
        "v_add_u32 v2, 0x1000, v1\n\t"              // +4096 for chunk 1
        "global_load_dwordx4 v[40:43], v1, %[pzb]\n\t"
        "global_load_dwordx4 v[44:47], v2, %[pzb]\n\t"
        "global_load_dwordx4 v[48:51], v1, %[pwi]\n\t"
        "global_load_dwordx4 v[52:55], v2, %[pwi]\n\t"
        "global_load_dwordx4 v[56:59], v1, %[pwq]\n\t"
        "global_load_dwordx4 v[60:63], v2, %[pwq]\n\t"
        "s_waitcnt vmcnt(0)\n\t"
        // scale biases by sigma_b
        "v_mul_f32 v40, %[osg], v40\n\t"  "v_mul_f32 v41, %[osg], v41\n\t"
        "v_mul_f32 v42, %[osg], v42\n\t"  "v_mul_f32 v43, %[osg], v43\n\t"
        "v_mul_f32 v44, %[osg], v44\n\t"  "v_mul_f32 v45, %[osg], v45\n\t"
        "v_mul_f32 v46, %[osg], v46\n\t"  "v_mul_f32 v47, %[osg], v47\n\t"
        // zero w_out state v64..v71
        "v_mov_b32 v64, 0\n\t" "v_mov_b32 v65, 0\n\t" "v_mov_b32 v66, 0\n\t" "v_mov_b32 v67, 0\n\t"
        "v_mov_b32 v68, 0\n\t" "v_mov_b32 v69, 0\n\t" "v_mov_b32 v70, 0\n\t" "v_mov_b32 v71, 0\n\t"
        // state: qlp v20, ylp v21, u v22, e v23, lr_mult v24, sp v25, rsp v26
        "v_mov_b32 v20, 0\n\t" "v_mov_b32 v21, 0\n\t" "v_mov_b32 v22, 0\n\t" "v_mov_b32 v23, 0\n\t"
        "v_mov_b32 v24, 1.0\n\t" "v_mov_b32 v25, 1.0\n\t" "v_mov_b32 v26, 1.0\n\t"
        "v_mov_b32 v6, %[ovo]\n\t"                  // out byte-offset
        "s_mov_b32 s60, 0\n\t"                      // t
        "s_mov_b32 s61, 12\n\t"                     // y/q byte off for t+3 issue
        "s_mov_b32 s62, 0x1800\n\t"                 // nz byte off for t+3 issue
        // scalar pipeline: A = t0 (s66-68), B = t1 (s69-71), C = t2 (s50-52)
        "s_load_dword s66, %[pys], 0x0\n\t"
        "s_load_dword s67, %[pqs], 0x0\n\t"
        "s_load_dword s68, %[pnz], 0x0\n\t"
        "s_load_dword s69, %[pys], 0x4\n\t"
        "s_load_dword s70, %[pqs], 0x4\n\t"
        "s_load_dword s71, %[pnz], 0x800\n\t"
        "s_load_dword s50, %[pys], 0x8\n\t"
        "s_load_dword s51, %[pqs], 0x8\n\t"
        "s_load_dword s52, %[pnz], 0x1000\n\t"
        "s_waitcnt lgkmcnt(0)\n\t"
        // ---------------- main scan loop ------------------------------------
        "Lelbo3:\n\t"
        // qlp = omtq*qlp + tauq*q ; qsc pair v[10:11]   (uses A: s67)
        "v_mov_b32 v30, s67\n\t"
        "v_mul_f32 v20, %[omq], v20\n\t"
        "v_fmac_f32 v20, %[otq], v30\n\t"
        "v_mul_f32 v10, %[oq], v20\n\t"
        "v_mov_b32 v11, v10\n\t"
        // x = e + nz + ufs*u ; pair v[8:9]   (uses A: s68)
        "v_mov_b32 v8, s68\n\t"
        "v_add_f32 v8, v23, v8\n\t"
        "v_fmac_f32 v8, %[ouf], v22\n\t"
        "v_mov_b32 v9, v8\n\t"
        // zero accumulators su v[12:13], sh v[14:15]
        "v_mov_b32 v12, 0\n\t" "v_mov_b32 v13, 0\n\t"
        "v_mov_b32 v14, 0\n\t" "v_mov_b32 v15, 0\n\t"
        // h = relu(cb + x*cw + qsc*cq)  (4 packed pairs)
        "v_pk_fma_f32 v[72:73], v[10:11], v[56:57], v[40:41]\n\t"
        "v_pk_fma_f32 v[74:75], v[10:11], v[58:59], v[42:43]\n\t"
        "v_pk_fma_f32 v[76:77], v[10:11], v[60:61], v[44:45]\n\t"
        "v_pk_fma_f32 v[78:79], v[10:11], v[62:63], v[46:47]\n\t"
        "v_pk_fma_f32 v[72:73], v[8:9], v[48:49], v[72:73]\n\t"
        "v_pk_fma_f32 v[74:75], v[8:9], v[50:51], v[74:75]\n\t"
        "v_pk_fma_f32 v[76:77], v[8:9], v[52:53], v[76:77]\n\t"
        "v_pk_fma_f32 v[78:79], v[8:9], v[54:55], v[78:79]\n\t"
        "v_max_f32 v72, 0, v72\n\t" "v_max_f32 v73, 0, v73\n\t"
        "v_max_f32 v74, 0, v74\n\t" "v_max_f32 v75, 0, v75\n\t"
        "v_max_f32 v76, 0, v76\n\t" "v_max_f32 v77, 0, v77\n\t"
        "v_max_f32 v78, 0, v78\n\t" "v_max_f32 v79, 0, v79\n\t"
        // su += v.h ; sh += h.h (interleaved chains)
        "v_pk_fma_f32 v[12:13], v[64:65], v[72:73], v[12:13]\n\t"
        "v_pk_fma_f32 v[14:15], v[72:73], v[72:73], v[14:15]\n\t"
        "v_pk_fma_f32 v[12:13], v[66:67], v[74:75], v[12:13]\n\t"
        "v_pk_fma_f32 v[14:15], v[74:75], v[74:75], v[14:15]\n\t"
        "v_pk_fma_f32 v[12:13], v[68:69], v[76:77], v[12:13]\n\t"
        "v_pk_fma_f32 v[14:15], v[76:77], v[76:77], v[14:15]\n\t"
        "v_pk_fma_f32 v[12:13], v[70:71], v[78:79], v[12:13]\n\t"
        "v_pk_fma_f32 v[14:15], v[78:79], v[78:79], v[14:15]\n\t"
        // horizontal: su v12, sh v14
        "v_add_f32 v12, v12, v13\n\t"
        "v_add_f32 v14, v14, v15\n\t"
        // wave reduce to lane 63 (DPP), su v12/tmp v30, sh v14/tmp v31
        "s_nop 1\n\t"
        "v_mov_b32_dpp v30, v12 row_shr:1 row_mask:0xf bank_mask:0xf\n\t"
        "v_mov_b32_dpp v31, v14 row_shr:1 row_mask:0xf bank_mask:0xf\n\t"
        "v_add_f32 v12, v12, v30\n\t"
        "v_add_f32 v14, v14, v31\n\t"
        "s_nop 0\n\t"
        "v_mov_b32_dpp v30, v12 row_shr:2 row_mask:0xf bank_mask:0xf\n\t"
        "v_mov_b32_dpp v31, v14 row_shr:2 row_mask:0xf bank_mask:0xf\n\t"
        "v_add_f32 v12, v12, v30\n\t"
        "v_add_f32 v14, v14, v31\n\t"
        "s_nop 0\n\t"
        "v_mov_b32_dpp v30, v12 row_shr:4 row_mask:0xf bank_mask:0xf\n\t"
        "v_mov_b32_dpp v31, v14 row_shr:4 row_mask:0xf bank_mask:0xf\n\t"
        "v_add_f32 v12, v12, v30\n\t"
        "v_add_f32 v14, v14, v31\n\t"
        "s_nop 0\n\t"
        "v_mov_b32_dpp v30, v12 row_shr:8 row_mask:0xf bank_mask:0xf\n\t"
        "v_mov_b32_dpp v31, v14 row_shr:8 row_mask:0xf bank_mask:0xf\n\t"
        "v_add_f32 v12, v12, v30\n\t"
        "v_add_f32 v14, v14, v31\n\t"
        "s_nop 0\n\t"
        "v_mov_b32_dpp v30, v12 row_bcast:15 row_mask:0xf bank_mask:0xf\n\t"
        "v_mov_b32_dpp v31, v14 row_bcast:15 row_mask:0xf bank_mask:0xf\n\t"
        "v_add_f32 v12, v12, v30\n\t"
        "v_add_f32 v14, v14, v31\n\t"
        "s_nop 0\n\t"
        "v_mov_b32_dpp v30, v12 row_bcast:31 row_mask:0xf bank_mask:0xf\n\t"
        "v_mov_b32_dpp v31, v14 row_bcast:31 row_mask:0xf bank_mask:0xf\n\t"
        "v_add_f32 v12, v12, v30\n\t"
        "v_add_f32 v14, v14, v31\n\t"
        "s_nop 1\n\t"
        // lane 63 publishes this wave's partials {su, sh} to LDS
        "s_and_saveexec_b64 s[72:73], s[74:75]\n\t"
        "ds_write2_b32 v4, v12, v14 offset0:0 offset1:1\n\t"
        "s_mov_b64 exec, s[72:73]\n\t"
        // drains ONLY the ds_write: all outstanding s_loads are >=1 step old
        "s_waitcnt lgkmcnt(0)\n\t"
        "s_barrier\n\t"
        "ds_read_b128 v[32:35], v5\n\t"
        "ds_read_b128 v[36:39], v5 offset:16\n\t"
        // ---- ds_read shadow: all independent of the read ----
        "v_mov_b32 v30, s66\n\t"                    // y_t (A, pre-rotation)
        "v_mul_f32 v21, %[omy], v21\n\t"
        "v_fmac_f32 v21, %[oty], v30\n\t"           // ylp updated
        "v_xor_b32 v4, 32, v4\n\t"                  // parity toggle
        "v_xor_b32 v5, 32, v5\n\t"
        "s_mov_b32 s66, s69\n\t"                    // rotate A <- B
        "s_mov_b32 s67, s70\n\t"
        "s_mov_b32 s68, s71\n\t"
        "s_mov_b32 s69, s50\n\t"                    // rotate B <- C (drained)
        "s_mov_b32 s70, s51\n\t"
        "s_mov_b32 s71, s52\n\t"
        "s_add_u32 s60, s60, 1\n\t"
        // ---- end shadow ----
        "s_waitcnt lgkmcnt(0)\n\t"
        "v_pk_add_f32 v[32:33], v[32:33], v[34:35]\n\t"
        "v_pk_add_f32 v[36:37], v[36:37], v[38:39]\n\t"
        "v_pk_add_f32 v[32:33], v[32:33], v[36:37]\n\t"   // su_t v32, sh_t v33
        // u = sp * su_t ; store oscale*u from tid 0 (exec-predicated)
        "v_mul_f32 v22, v25, v32\n\t"
        "v_mul_f32 v30, %[oos], v22\n\t"
        "s_and_saveexec_b64 s[72:73], s[76:77]\n\t"
        "global_store_dword v6, v30, %[pou]\n\t"
        "s_mov_b64 exec, s[72:73]\n\t"
        "v_add_u32 v6, 0x800, v6\n\t"               // next row (+BS*4)
        // e, el, c
        "v_sub_f32 v23, v21, v22\n\t"               // e = ylp - u
        "v_mul_f32 v27, %[olr], v23\n\t"
        "v_mul_f32 v27, v27, v24\n\t"               // el
        "v_mul_f32 v28, v27, v26\n\t"               // c = el*rsp
        "v_mov_b32 v29, v28\n\t"
        // issue C <- scalars(t+3) AFTER the last lgkm drain of this step
        "s_load_dword s50, %[pys], s61\n\t"
        "s_load_dword s51, %[pqs], s61\n\t"
        "s_load_dword s52, %[pnz], s62\n\t"
        "s_add_u32 s61, s61, 4\n\t"
        "s_min_u32 s61, s61, 0x3fc\n\t"
        "s_add_u32 s62, s62, 0x800\n\t"
        "s_min_u32 s62, s62, 0x7f800\n\t"
        // v += c*h (4 packed)
        "v_pk_fma_f32 v[64:65], v[28:29], v[72:73], v[64:65]\n\t"
        "v_pk_fma_f32 v[66:67], v[28:29], v[74:75], v[66:67]\n\t"
        "v_pk_fma_f32 v[68:69], v[28:29], v[76:77], v[68:69]\n\t"
        "v_pk_fma_f32 v[70:71], v[28:29], v[78:79], v[70:71]\n\t"
        // lr_mult *= exp2(nld2 * sqrt(el^2*sh_t + FUDGE)) ; sp, rsp
        "v_mul_f32 v30, v27, v27\n\t"
        "v_mul_f32 v30, v33, v30\n\t"
        "v_add_f32 v30, 0x38d1b717, v30\n\t"        // + 1e-4f
        "v_sqrt_f32 v30, v30\n\t"
        "s_nop 1\n\t"
        "v_mul_f32 v30, %[ond], v30\n\t"
        "v_exp_f32 v30, v30\n\t"
        "s_nop 1\n\t"
        "v_mul_f32 v24, v24, v30\n\t"
        "v_mul_f32 v25, %[owd], v25\n\t"
        "v_mul_f32 v26, %[orw], v26\n\t"
        // loop
        "s_cmp_lt_u32 s60, 0x100\n\t"
        "s_cbranch_scc1 Lelbo3\n\t"
        "s_waitcnt vmcnt(0)\n\t"                    // drain stores
        :
        : [pys]"s"(ys), [pqs]"s"(qs), [pnz]"s"(nzp), [pou]"s"(out),
          [pzb]"s"(z_biases), [pwi]"s"(w_in), [pwq]"s"(w_inq),
          [vtid]"v"(tid), [ovo]"v"(ovo),
          [osg]"v"(sigb), [otq]"v"(tauq), [omq]"v"(omtq),
          [oty]"v"(tauy), [omy]"v"(omty), [oq]"v"(qscale),
          [ouf]"v"(ufs), [olr]"v"(lr0), [owd]"v"(wd), [orw]"v"(rwd),
          [oos]"v"(oscale), [ond]"v"(nld2)
        : "memory", "scc", "vcc",
          "s50","s51","s52",
          "s60","s61","s62","s63","s64","s65","s66","s67","s68","s69",
          "s70","s71","s72","s73","s74","s75","s76","s77",
          "v1","v2","v3","v4","v5","v6","v7","v8","v9","v10","v11",
          "v12","v13","v14","v15","v16","v17","v18","v19","v20","v21",
          "v22","v23","v24","v25","v26","v27","v28","v29","v30","v31",
          "v32","v33","v34","v35","v36","v37","v38","v39","v40","v41",
          "v42","v43","v44","v45","v46","v47","v48","v49","v50","v51",
          "v52","v53","v54","v55","v56","v57","v58","v59","v60","v61",
          "v62","v63","v64","v65","v66","v67","v68","v69","v70","v71",
          "v72","v73","v74","v75","v76","v77","v78","v79"
    );
}

extern "C" void kernel_launch(void* const* d_in, const int* in_sizes, int n_in,
                              void* d_out, int out_size, void* d_ws, size_t ws_size,
                              hipStream_t stream) {
    (void)in_sizes; (void)n_in; (void)d_ws; (void)ws_size; (void)out_size;
    const float* noises   = (const float*)d_in[0];
    const float* ys       = (const float*)d_in[1];
    const float* qs       = (const float*)d_in[2];
    const float* z_biases = (const float*)d_in[3];
    const float* w_in     = (const float*)d_in[4];
    const float* w_inq    = (const float*)d_in[5];
    const float* llr      = (const float*)d_in[6];
    const float* llrd     = (const float*)d_in[7];
    const float* sigb     = (const float*)d_in[8];
    const float* oscale   = (const float*)d_in[9];
    const float* ufs      = (const float*)d_in[10];
    const float* lwd      = (const float*)d_in[11];
    const float* qscale   = (const float*)d_in[12];
    const float* tauq     = (const float*)d_in[13];
    const float* tauy     = (const float*)d_in[14];
    float* out = (float*)d_out;

    // 64 B dynamic LDS: keeps raw ds addresses 0..63 valid even if the
    // compiler were to drop the static red_lds allocation.
    hipLaunchKernelGGL(legacy_elbo_scan_kernel, dim3(BS), dim3(BLOCK), 64, stream,
                       noises, ys, qs, z_biases, w_in, w_inq,
                       llr, llrd, sigb, oscale, ufs, lwd, qscale, tauq, tauy,
                       out);
}